// Round 9
// baseline (97.919 us; speedup 1.0000x reference)
//
#include <hip/hip_runtime.h>
#include <math.h>

// Hungarian matcher cost matrix:
//   C[n,t] = 5*L1(xyxy) + 2*(focal@label[t]) - 2*GIoU + 9999*inner
// N = 14400, T = 1024, C = 91. Output [N,T] f32 (59 MB).
//
// R9 = R8 + NONTEMPORAL coalesced stores.
// Wall analysis: every variant's stores ran at ~1.33 TB/s (57.6MB -> 43us),
// the same rate as the harness's out-poison fill when it hits L3 (44us fill
// with WRITE_SIZE~0). Writes hitting DIRTY L3-resident lines (the 0xAA
// poison) are capped ~1.3 TB/s; miss-and-evict writes run 6.2 TB/s.
// nt stores bypass the dirty-line hit path.

typedef float nfloat4 __attribute__((ext_vector_type(4)));

#define BN 8
#define BT 256
#define VT 4

__global__ __launch_bounds__(BT) void matcher_kernel(
    const float* __restrict__ logits,   // [N, C]
    const float* __restrict__ boxes,    // [N, 4] cxcywh
    const float* __restrict__ points,   // [N, 2]
    const float* __restrict__ objs,     // [N, 1]
    const int*   __restrict__ labels,   // [T]
    const float* __restrict__ tboxes,   // [T, 4] cxcywh
    float* __restrict__ out,            // [N, T]
    int N, int C, int T)
{
    __shared__ float s_tab[96 * BN];   // TRANSPOSED: s_tab[c*8 + r]
    __shared__ float s_row[BN][8];     // x0,y0,x1,y1 | px,py,area1,po

    const int tid = threadIdx.x;
    const int rowBase = blockIdx.y * BN;
    const int t0 = tid * VT;

    // ---- Phase 1a: per-row constants ----
    if (tid < BN) {
        int n = rowBase + tid;
        float4 b = *(const float4*)(boxes + 4 * n);
        float x0 = b.x - 0.5f * b.z;
        float y0 = b.y - 0.5f * b.w;
        float x1 = b.x + 0.5f * b.z;
        float y1 = b.y + 0.5f * b.w;
        s_row[tid][0] = x0;
        s_row[tid][1] = y0;
        s_row[tid][2] = x1;
        s_row[tid][3] = y1;
        float2 p = *(const float2*)(points + 2 * n);
        s_row[tid][4] = p.x;
        s_row[tid][5] = p.y;
        s_row[tid][6] = (x1 - x0) * (y1 - y0);
        s_row[tid][7] = __builtin_amdgcn_rcpf(1.0f + __expf(-objs[n]));
    }
    __syncthreads();

    // ---- Phase 1b: focal table, transposed write s_tab[c*8+r] ----
    for (int idx = tid; idx < BN * C; idx += BT) {
        int r = idx / C;
        int c = idx - r * C;
        float lg = logits[(size_t)rowBase * C + idx];
        float ps = __builtin_amdgcn_rcpf(1.0f + __expf(-lg));
        float p = ps * s_row[r][7];
        float omp = 1.0f - p;
        float pos = 0.25f * (omp * omp) * (-__logf(p + 1e-8f));
        float neg = 0.75f * (p * p) * (-__logf(omp + 1e-8f));
        s_tab[c * BN + r] = pos - neg;
    }
    __syncthreads();

    // ---- Phase 2: 4 target columns x 8 rows per thread ----
    {
        int4 lv = *(const int4*)(labels + t0);
        int lab[VT] = {lv.x, lv.y, lv.z, lv.w};
        float tx0[VT], ty0[VT], tx1[VT], ty1[VT], tarea[VT];
        #pragma unroll
        for (int j = 0; j < VT; ++j) {
            float4 tb = *(const float4*)(tboxes + 4 * (t0 + j));
            tx0[j] = tb.x - 0.5f * tb.z;
            ty0[j] = tb.y - 0.5f * tb.w;
            tx1[j] = tb.x + 0.5f * tb.z;
            ty1[j] = tb.y + 0.5f * tb.w;
            tarea[j] = (tx1[j] - tx0[j]) * (ty1[j] - ty0[j]);
        }

        // class costs: per j, all 8 rows in 2 ds_read_b128 (16B-aligned)
        float cc[VT][BN];
        #pragma unroll
        for (int j = 0; j < VT; ++j) {
            const float4* tp = (const float4*)(s_tab + lab[j] * BN);
            float4 lo = tp[0];
            float4 hi = tp[1];
            cc[j][0] = lo.x; cc[j][1] = lo.y; cc[j][2] = lo.z; cc[j][3] = lo.w;
            cc[j][4] = hi.x; cc[j][5] = hi.y; cc[j][6] = hi.z; cc[j][7] = hi.w;
        }

        // row constants -> registers (broadcast b128 reads)
        float rx0[BN], ry0[BN], rx1[BN], ry1[BN], rpx[BN], rpy[BN], ra1[BN];
        #pragma unroll
        for (int r = 0; r < BN; ++r) {
            float4 ra = *(const float4*)&s_row[r][0];
            float4 rb = *(const float4*)&s_row[r][4];
            rx0[r] = ra.x; ry0[r] = ra.y; rx1[r] = ra.z; ry1[r] = ra.w;
            rpx[r] = rb.x; rpy[r] = rb.y; ra1[r] = rb.z;
        }

        float* obase = out + (size_t)rowBase * T + t0;
        #pragma unroll
        for (int r = 0; r < BN; ++r) {
            float x0 = rx0[r], y0 = ry0[r], x1 = rx1[r], y1 = ry1[r];
            float px = rpx[r], py = rpy[r], a1 = ra1[r];

            nfloat4 res;
            #pragma unroll
            for (int j = 0; j < VT; ++j) {
                // L1 on xyxy
                float l1 = fabsf(x0 - tx0[j]) + fabsf(y0 - ty0[j])
                         + fabsf(x1 - tx1[j]) + fabsf(y1 - ty1[j]);

                // intersection / union
                float iw = fminf(x1, tx1[j]) - fmaxf(x0, tx0[j]);
                float ih = fminf(y1, ty1[j]) - fmaxf(y0, ty0[j]);
                float inter = fmaxf(iw, 0.0f) * fmaxf(ih, 0.0f);
                float uni = (a1 + tarea[j]) - inter;

                // enclosing box (extents >= 0 since w,h >= 0)
                float cw = fmaxf(x1, tx1[j]) - fminf(x0, tx0[j]);
                float ch = fmaxf(y1, ty1[j]) - fminf(y0, ty0[j]);
                float carea = cw * ch;

                // giou with a single rcp: R = 1/(uni*carea)
                float R = __builtin_amdgcn_rcpf(uni * carea);
                float giou = (inter * carea - uni * (carea - uni)) * R;

                // inner-point: exact reference op sequence (sign-exact)
                float left = px - tx0[j];
                float top = py - ty0[j];
                float right = tx1[j] - px;
                float bottom = ty1[j] - py;
                float mind = fminf(fminf(left, top), fminf(right, bottom));

                float Cv = fmaf(5.0f, l1, fmaf(2.0f, cc[j][r], -2.0f * giou));
                Cv += (mind >= 0.0f) ? 0.0f : 9999.0f;
                res[j] = Cv;
            }
            // nontemporal: bypass the dirty-L3 write-hit path (MUBUF nt)
            __builtin_nontemporal_store(res, (nfloat4*)(obase + (size_t)r * T));
        }
    }
}

extern "C" void kernel_launch(void* const* d_in, const int* in_sizes, int n_in,
                              void* d_out, int out_size, void* d_ws, size_t ws_size,
                              hipStream_t stream) {
    const float* logits = (const float*)d_in[0];  // [bs,nq,nc]
    const float* boxes  = (const float*)d_in[1];  // [bs,nq,4]
    const float* points = (const float*)d_in[2];  // [bs,nq,2]
    const float* objs   = (const float*)d_in[3];  // [bs,nq,1]
    const int*   labels = (const int*)d_in[4];    // [T]
    const float* tboxes = (const float*)d_in[5];  // [T,4]
    float* out = (float*)d_out;

    int N = in_sizes[1] / 4;        // 14400
    int T = in_sizes[5] / 4;        // 1024
    int C = in_sizes[0] / N;        // 91

    dim3 grid(1, N / BN);           // 1800 blocks; each covers 8 rows x 1024 cols
    matcher_kernel<<<grid, BT, 0, stream>>>(logits, boxes, points, objs,
                                            labels, tboxes, out, N, C, T);
}